// Round 5
// baseline (1969.927 us; speedup 1.0000x reference)
//
#include <hip/hip_runtime.h>

#define H 64
#define BSHIFT 7
#define BUCKET 128

__device__ __forceinline__ int bcasti(int x, int j) {
    return __builtin_amdgcn_readlane(x, j);
}
__device__ __forceinline__ float bcastf(float x, int j) {
    return __uint_as_float((unsigned)__builtin_amdgcn_readlane((int)__float_as_uint(x), j));
}

__global__ void fill_zero(float* __restrict__ p, int n) {
    int i = blockIdx.x * blockDim.x + threadIdx.x;
    int stride = gridDim.x * blockDim.x;
    for (; i < n; i += stride) p[i] = 0.f;
}

// v2 = Wd @ a_d
__global__ void wvec_kernel(const float* __restrict__ Wd, const float* __restrict__ ad_,
                            float* __restrict__ v2) {
    int k = threadIdx.x;
    float s2 = 0.f;
    for (int j = 0; j < H; ++j) s2 += Wd[k * H + j] * ad_[j];
    v2[k] = s2;
}

// hs = x @ W ; ssrc = hs . a_s   (one wave per row, W in LDS)
__global__ void gemm_hs_fused(const float* __restrict__ x, const float* __restrict__ W,
                              const float* __restrict__ as_, float* __restrict__ hs,
                              float* __restrict__ ssrc, int n) {
    __shared__ float Wl[H * H];
    int t = threadIdx.x;
    for (int i = t; i < H * H; i += 256) Wl[i] = W[i];
    __syncthreads();
    int row = blockIdx.x * 4 + (t >> 6);
    int lane = t & 63;
    if (row >= n) return;
    float xr = x[(size_t)row * H + lane];
    float acc = 0.f;
#pragma unroll
    for (int k = 0; k < H; ++k) {
        acc += bcastf(xr, k) * Wl[k * H + lane];
    }
    hs[(size_t)row * H + lane] = acc;
    float p = acc * as_[lane];
#pragma unroll
    for (int off = 32; off; off >>= 1) p += __shfl_xor(p, off);
    if (lane == 0) ssrc[row] = p;
}

// ---- bucketed CSR build ----
// 1) bucket histogram
__global__ void bhist_kernel(const int* __restrict__ dst, int* __restrict__ bcnt, int ne) {
    int i = blockIdx.x * blockDim.x + threadIdx.x;
    int stride = gridDim.x * blockDim.x;
    for (; i < ne; i += stride) atomicAdd(&bcnt[dst[i] >> BSHIFT], 1);
}

// 2) exclusive scan of bucket counts (nb <= 1024), writes bstart[0..nb] and bcur
__global__ void bucket_scan(const int* __restrict__ bcnt, int* __restrict__ bstart,
                            int* __restrict__ bcur, int nb, int ne) {
    __shared__ int sm[1024];
    int t = threadIdx.x;
    int c = t < nb ? bcnt[t] : 0;
    sm[t] = c;
    __syncthreads();
    for (int off = 1; off < 1024; off <<= 1) {
        int v = t >= off ? sm[t - off] : 0;
        __syncthreads();
        sm[t] += v;
        __syncthreads();
    }
    if (t < nb) { int e = sm[t] - c; bstart[t] = e; bcur[t] = e; }
    if (t == 0) bstart[nb] = ne;
}

// 3) pass A: scatter (dst,src) records into bucket regions (8B stores, dense regions)
__global__ void bucket_scatter(const int* __restrict__ src, const int* __restrict__ dst,
                               int* __restrict__ bcur, unsigned long long* __restrict__ tmp, int ne) {
    int i = blockIdx.x * blockDim.x + threadIdx.x;
    int stride = gridDim.x * blockDim.x;
    for (; i < ne; i += stride) {
        int d = dst[i];
        int pos = atomicAdd(&bcur[d >> BSHIFT], 1);
        unsigned long long rec = ((unsigned long long)(unsigned)d << 32) | (unsigned)src[i];
        __builtin_nontemporal_store(rec, &tmp[pos]);
    }
}

// 4) pass B: one block per bucket; LDS count+scan of its 128 dsts, emit rowptr,
//    then local re-scatter of src into final CSR position (L2-hot window).
__global__ void bucket_finalize(const unsigned long long* __restrict__ tmp,
                                const int* __restrict__ bstart,
                                int* __restrict__ rowptr, int* __restrict__ srcs_sorted,
                                int ndst, int nb, int ne) {
    __shared__ int cnt[BUCKET];
    __shared__ int sm[BUCKET];
    __shared__ int cur[BUCKET];
    int b = blockIdx.x;
    int t = threadIdx.x;
    int base = bstart[b], endi = bstart[b + 1];
    if (t < BUCKET) cnt[t] = 0;
    __syncthreads();
    for (int i = base + t; i < endi; i += 256) {
        int d = (int)(tmp[i] >> 32);
        atomicAdd(&cnt[d & (BUCKET - 1)], 1);
    }
    __syncthreads();
    if (t < BUCKET) sm[t] = cnt[t];
    __syncthreads();
    for (int off = 1; off < BUCKET; off <<= 1) {
        int v = (t < BUCKET && t >= off) ? sm[t - off] : 0;
        __syncthreads();
        if (t < BUCKET) sm[t] += v;
        __syncthreads();
    }
    int d0 = b << BSHIFT;
    if (t < BUCKET) {
        int e = base + sm[t] - cnt[t];
        cur[t] = e;
        if (d0 + t < ndst) rowptr[d0 + t] = e;
    }
    if (t == 0) {
        int hi = d0 + BUCKET;
        if (hi > ndst) hi = ndst;
        rowptr[hi] = endi;
    }
    __syncthreads();
    for (int i = base + t; i < endi; i += 256) {
        unsigned long long rec = tmp[i];
        int d = (int)(rec >> 32);
        int s = (int)(rec & 0xffffffffu);
        int pos = atomicAdd(&cur[d & (BUCKET - 1)], 1);
        srcs_sorted[pos] = s;
    }
}

// ---- fused per-dst-node GAT aggregation, two-phase softmax, readlane broadcast ----
__device__ __forceinline__ float gat_aggregate(const int* __restrict__ rowptr,
                                               const int* __restrict__ srcs,
                                               const float* __restrict__ ssrc,
                                               const float* __restrict__ xdst,
                                               const float* __restrict__ v2,
                                               const float* __restrict__ hs,
                                               const float* __restrict__ bias,
                                               int wid, int lane) {
    float p = xdst[(size_t)wid * H + lane] * v2[lane];
#pragma unroll
    for (int off = 32; off; off >>= 1) p += __shfl_xor(p, off);
    float sdst = p;

    int beg = rowptr[wid], end = rowptr[wid + 1];
    int cnt = end - beg;
    float acc0 = 0.f, acc1 = 0.f, l;

    if (cnt <= 64) {
        bool valid = lane < cnt;
        int s_l = valid ? srcs[beg + lane] : 0;
        float sc = ssrc[s_l] + sdst;
        sc = sc > 0.f ? sc : 0.2f * sc;
        float mm = valid ? sc : -3.4e38f;
#pragma unroll
        for (int off = 32; off; off >>= 1) mm = fmaxf(mm, __shfl_xor(mm, off));
        float ev_l = valid ? __expf(sc - mm) : 0.f;
        float ll = ev_l;
#pragma unroll
        for (int off = 32; off; off >>= 1) ll += __shfl_xor(ll, off);
        l = ll;
        int j = 0;
        for (; j + 1 < cnt; j += 2) {
            int s0 = bcasti(s_l, j), s1 = bcasti(s_l, j + 1);
            float e0 = bcastf(ev_l, j), e1 = bcastf(ev_l, j + 1);
            acc0 += e0 * hs[(size_t)s0 * H + lane];
            acc1 += e1 * hs[(size_t)s1 * H + lane];
        }
        if (j < cnt) acc0 += bcastf(ev_l, j) * hs[(size_t)bcasti(s_l, j) * H + lane];
    } else {
        float mm = -3.4e38f;
        for (int base = beg; base < end; base += 64) {
            int idx = base + lane;
            if (idx < end) {
                float sc = ssrc[srcs[idx]] + sdst;
                sc = sc > 0.f ? sc : 0.2f * sc;
                mm = fmaxf(mm, sc);
            }
        }
#pragma unroll
        for (int off = 32; off; off >>= 1) mm = fmaxf(mm, __shfl_xor(mm, off));
        float ll = 0.f;
        for (int base = beg; base < end; base += 64) {
            int idx = base + lane;
            int c2 = end - base; if (c2 > 64) c2 = 64;
            int s_l = idx < end ? srcs[idx] : 0;
            float ev_l = 0.f;
            if (idx < end) {
                float sc = ssrc[s_l] + sdst;
                sc = sc > 0.f ? sc : 0.2f * sc;
                ev_l = __expf(sc - mm);
            }
            ll += ev_l;
            for (int j = 0; j < c2; ++j) {
                acc0 += bcastf(ev_l, j) * hs[(size_t)bcasti(s_l, j) * H + lane];
            }
        }
#pragma unroll
        for (int off = 32; off; off >>= 1) ll += __shfl_xor(ll, off);
        l = ll;
    }
    float v = (acc0 + acc1) / (l + 1e-16f) + bias[lane];
    return v > 0.f ? v : 0.f;
}

__global__ void gat_node_kernel(const int* __restrict__ rowptr, const int* __restrict__ srcs,
                                const float* __restrict__ ssrc, const float* __restrict__ xdst,
                                const float* __restrict__ v2, const float* __restrict__ hs,
                                const float* __restrict__ bias, float* __restrict__ out, int ndst) {
    int wid = (int)((blockIdx.x * blockDim.x + threadIdx.x) >> 6);
    int lane = threadIdx.x & 63;
    if (wid >= ndst) return;
    out[(size_t)wid * H + lane] = gat_aggregate(rowptr, srcs, ssrc, xdst, v2, hs, bias, wid, lane);
}

// final relation: GAT aggregation + fused MLP head
__global__ void gat_node_mlp_kernel(const int* __restrict__ rowptr, const int* __restrict__ srcs,
                                    const float* __restrict__ ssrc, const float* __restrict__ xdst,
                                    const float* __restrict__ v2, const float* __restrict__ hs,
                                    const float* __restrict__ bias,
                                    const float* __restrict__ w1, const float* __restrict__ b1,
                                    const float* __restrict__ w2, const float* __restrict__ b2,
                                    float* __restrict__ out, int ndst) {
    __shared__ float W1[H * 32];
    __shared__ float W2[32];
    __shared__ float B1[32];
    {
        int t = threadIdx.x;
        for (int i = t; i < H * 32; i += 256) W1[i] = w1[i];
        if (t < 32) { W2[t] = w2[t]; B1[t] = b1[t]; }
        __syncthreads();
    }
    int wid = (int)((blockIdx.x * blockDim.x + threadIdx.x) >> 6);
    int lane = threadIdx.x & 63;
    if (wid >= ndst) return;
    float v = gat_aggregate(rowptr, srcs, ssrc, xdst, v2, hs, bias, wid, lane);

    int c = lane & 31;
    int kbase = (lane >> 5) << 5;
    float s = 0.f;
#pragma unroll
    for (int k = 0; k < 32; ++k) s += __shfl(v, kbase + k) * W1[(kbase + k) * 32 + c];
    s += __shfl_xor(s, 32);
    s += B1[c];
    s = s > 0.f ? s : 0.f;
    float q = s * W2[c];
#pragma unroll
    for (int off = 16; off; off >>= 1) q += __shfl_xor(q, off);
    if (lane == 0) out[wid] = q + b2[0];
}

extern "C" void kernel_launch(void* const* d_in, const int* in_sizes, int n_in,
                              void* d_out, int out_size, void* d_ws, size_t ws_size,
                              hipStream_t stream) {
    const float* x_inst  = (const float*)d_in[0];
    const float* x_net   = (const float*)d_in[1];
    const int*   e_i2n   = (const int*)d_in[2];
    const int*   e_n2i   = (const int*)d_in[3];
    const float* W_src   = (const float*)d_in[4];
    const float* W_dst   = (const float*)d_in[5];
    const float* att_src = (const float*)d_in[6];
    const float* att_dst = (const float*)d_in[7];
    const float* bias_g  = (const float*)d_in[8];
    const float* lin1_w  = (const float*)d_in[9];
    const float* lin1_b  = (const float*)d_in[10];
    const float* lin2_w  = (const float*)d_in[11];
    const float* lin2_b  = (const float*)d_in[12];

    const int n_inst = in_sizes[0] / H;
    const int n_net  = in_sizes[1] / H;
    const int ne     = in_sizes[2] / 2;
    const int nmax   = n_inst > n_net ? n_inst : n_net;

    float* ws = (float*)d_ws;
    size_t off = 0;
    auto alloc = [&](size_t nelem) {
        off = (off + 1) & ~(size_t)1;   // keep 8B alignment available
        float* p = ws + off; off += nelem; return p;
    };
    float* xnA     = alloc((size_t)n_net * H);
    float* xiA     = alloc((size_t)n_inst * H);
    float* hs      = alloc((size_t)nmax * H);
    float* ssrc    = alloc(nmax);
    int*   rp_i2n  = (int*)alloc(nmax + 1);
    int*   sr_i2n  = (int*)alloc(ne);
    int*   rp_n2i  = (int*)alloc(nmax + 1);
    int*   sr_n2i  = (int*)alloc(ne);
    unsigned long long* tmp = (unsigned long long*)alloc((size_t)ne * 2); // 8B records
    int*   bcnt    = (int*)alloc(1025);
    int*   bstart  = (int*)alloc(1025);
    int*   bcur    = (int*)alloc(1025);
    float* v2      = alloc(H);
    (void)ws_size;

    auto build_csr = [&](const int* esrc, const int* edst, int ndst,
                         int* rowptr, int* srcs) {
        int nb = (ndst + BUCKET - 1) >> BSHIFT;
        fill_zero<<<4, 256, 0, stream>>>((float*)bcnt, nb);
        bhist_kernel<<<2048, 256, 0, stream>>>(edst, bcnt, ne);
        bucket_scan<<<1, 1024, 0, stream>>>(bcnt, bstart, bcur, nb, ne);
        bucket_scatter<<<2048, 256, 0, stream>>>(esrc, edst, bcur, tmp, ne);
        bucket_finalize<<<nb, 256, 0, stream>>>(tmp, bstart, rowptr, srcs, ndst, nb, ne);
    };

    build_csr(e_i2n, e_i2n + ne, n_net, rp_i2n, sr_i2n);
    build_csr(e_n2i, e_n2i + ne, n_inst, rp_n2i, sr_n2i);

    auto proj = [&](const float* xsrc, int nsrc, int li, int ri) {
        const float* Ws  = W_src + (size_t)(li * 2 + ri) * H * H;
        const float* Wd  = W_dst + (size_t)(li * 2 + ri) * H * H;
        const float* as_ = att_src + (size_t)(li * 2 + ri) * H;
        const float* ad_ = att_dst + (size_t)(li * 2 + ri) * H;
        wvec_kernel<<<1, 64, 0, stream>>>(Wd, ad_, v2);
        gemm_hs_fused<<<(nsrc + 3) / 4, 256, 0, stream>>>(xsrc, Ws, as_, hs, ssrc, nsrc);
    };

    // layer 0, relation 0: inst -> net
    proj(x_inst, n_inst, 0, 0);
    gat_node_kernel<<<(n_net + 3) / 4, 256, 0, stream>>>(rp_i2n, sr_i2n, ssrc, x_net, v2,
                                                         hs, bias_g + 0 * H, xnA, n_net);
    // layer 0, relation 1: net -> inst
    proj(x_net, n_net, 0, 1);
    gat_node_kernel<<<(n_inst + 3) / 4, 256, 0, stream>>>(rp_n2i, sr_n2i, ssrc, x_inst, v2,
                                                          hs, bias_g + 1 * H, xiA, n_inst);
    // layer 1, relation 0: inst -> net, fused with MLP head (inst-side l1 is dead)
    proj(xiA, n_inst, 1, 0);
    gat_node_mlp_kernel<<<(n_net + 3) / 4, 256, 0, stream>>>(rp_i2n, sr_i2n, ssrc, xnA, v2,
                                                             hs, bias_g + 2 * H,
                                                             lin1_w, lin1_b, lin2_w, lin2_b,
                                                             (float*)d_out, n_net);
}

// Round 6
// 794.233 us; speedup vs baseline: 2.4803x; 2.4803x over previous
//
#include <hip/hip_runtime.h>
#include <hip/hip_fp16.h>

#define H 64

__device__ __forceinline__ int bcasti(int x, int j) {
    return __builtin_amdgcn_readlane(x, j);
}
__device__ __forceinline__ float bcastf(float x, int j) {
    return __uint_as_float((unsigned)__builtin_amdgcn_readlane((int)__float_as_uint(x), j));
}

__global__ void fill_zero(float* __restrict__ p, int n) {
    int i = blockIdx.x * blockDim.x + threadIdx.x;
    int stride = gridDim.x * blockDim.x;
    for (; i < n; i += stride) p[i] = 0.f;
}

// v2all[b][k] = sum_j Wd_b[k][j] * ad_b[j]  for the 3 used relations (flat idx 0,1,2)
__global__ void wvec3_kernel(const float* __restrict__ W_dst, const float* __restrict__ att_dst,
                             float* __restrict__ v2all) {
    int b = blockIdx.x;              // relation flat index 0..2
    int k = threadIdx.x;
    const float* Wd = W_dst + (size_t)b * H * H;
    const float* ad = att_dst + (size_t)b * H;
    float s2 = 0.f;
    for (int j = 0; j < H; ++j) s2 += Wd[k * H + j] * ad[j];
    v2all[b * H + k] = s2;
}

// hs = half(x @ W) ; ssrc = (x@W) . a_s   (one wave per row, W in LDS)
__global__ void gemm_hs_fused(const float* __restrict__ x, const float* __restrict__ W,
                              const float* __restrict__ as_, __half* __restrict__ hs,
                              float* __restrict__ ssrc, int n) {
    __shared__ float Wl[H * H];
    int t = threadIdx.x;
    for (int i = t; i < H * H; i += 256) Wl[i] = W[i];
    __syncthreads();
    int row = blockIdx.x * 4 + (t >> 6);
    int lane = t & 63;
    if (row >= n) return;
    float xr = x[(size_t)row * H + lane];
    float acc = 0.f;
#pragma unroll
    for (int k = 0; k < H; ++k) {
        acc += bcastf(xr, k) * Wl[k * H + lane];
    }
    hs[(size_t)row * H + lane] = __float2half_rn(acc);
    float p = acc * as_[lane];
#pragma unroll
    for (int off = 32; off; off >>= 1) p += __shfl_xor(p, off);
    if (lane == 0) ssrc[row] = p;
}

// ---- CSR build (wide cursors: low contention) ----
__global__ void hist2_kernel(const int* __restrict__ dst1, const int* __restrict__ dst2,
                             int* __restrict__ cnt1, int* __restrict__ cnt2, int ne) {
    int i = blockIdx.x * blockDim.x + threadIdx.x;
    int stride = gridDim.x * blockDim.x;
    int total = 2 * ne;
    for (; i < total; i += stride) {
        if (i < ne) atomicAdd(&cnt1[dst1[i]], 1);
        else        atomicAdd(&cnt2[dst2[i - ne]], 1);
    }
}

__global__ void scan_block(const int* __restrict__ count, int* __restrict__ excl,
                           int* __restrict__ bsum, int n) {
    __shared__ int sm[256];
    int t = threadIdx.x;
    int i = blockIdx.x * 256 + t;
    int c = i < n ? count[i] : 0;
    sm[t] = c;
    __syncthreads();
    for (int off = 1; off < 256; off <<= 1) {
        int v = t >= off ? sm[t - off] : 0;
        __syncthreads();
        sm[t] += v;
        __syncthreads();
    }
    if (i < n) excl[i] = sm[t] - c;
    if (t == 255) bsum[blockIdx.x] = sm[255];
}

__global__ void scan_bsum(int* __restrict__ bsum, int nb) {
    __shared__ int sm[1024];
    int t = threadIdx.x;
    int c = t < nb ? bsum[t] : 0;
    sm[t] = c;
    __syncthreads();
    for (int off = 1; off < 1024; off <<= 1) {
        int v = t >= off ? sm[t - off] : 0;
        __syncthreads();
        sm[t] += v;
        __syncthreads();
    }
    if (t < nb) bsum[t] = sm[t] - c;
}

__global__ void add_offsets(int* __restrict__ rowptr, const int* __restrict__ bsum,
                            int* __restrict__ cursor, int n, int ne) {
    int i = blockIdx.x * blockDim.x + threadIdx.x;
    if (i < n) {
        int r = rowptr[i] + bsum[i >> 8];
        rowptr[i] = r;
        cursor[i] = r;
    }
    if (i == n) rowptr[n] = ne;
}

__global__ void scatter2_kernel(const int* __restrict__ src1, const int* __restrict__ dst1,
                                int* __restrict__ cur1, int* __restrict__ out1,
                                const int* __restrict__ src2, const int* __restrict__ dst2,
                                int* __restrict__ cur2, int* __restrict__ out2, int ne) {
    int i = blockIdx.x * blockDim.x + threadIdx.x;
    int stride = gridDim.x * blockDim.x;
    int total = 2 * ne;
    for (; i < total; i += stride) {
        if (i < ne) {
            int pos = atomicAdd(&cur1[dst1[i]], 1);
            __builtin_nontemporal_store(src1[i], &out1[pos]);
        } else {
            int j = i - ne;
            int pos = atomicAdd(&cur2[dst2[j]], 1);
            __builtin_nontemporal_store(src2[j], &out2[pos]);
        }
    }
}

// ---- fused per-dst-node GAT aggregation, two-phase softmax, fp16 hs gather ----
__device__ __forceinline__ float gat_aggregate(const int* __restrict__ rowptr,
                                               const int* __restrict__ srcs,
                                               const float* __restrict__ ssrc,
                                               const float* __restrict__ xdst,
                                               const float* __restrict__ v2,
                                               const __half* __restrict__ hs,
                                               const float* __restrict__ bias,
                                               int wid, int lane) {
    float p = xdst[(size_t)wid * H + lane] * v2[lane];
#pragma unroll
    for (int off = 32; off; off >>= 1) p += __shfl_xor(p, off);
    float sdst = p;

    int beg = rowptr[wid], end = rowptr[wid + 1];
    int cnt = end - beg;
    float acc0 = 0.f, acc1 = 0.f, acc2 = 0.f, acc3 = 0.f, l;

    if (cnt <= 64) {
        bool valid = lane < cnt;
        int s_l = valid ? srcs[beg + lane] : 0;
        float sc = ssrc[s_l] + sdst;
        sc = sc > 0.f ? sc : 0.2f * sc;
        float mm = valid ? sc : -3.4e38f;
#pragma unroll
        for (int off = 32; off; off >>= 1) mm = fmaxf(mm, __shfl_xor(mm, off));
        float ev_l = valid ? __expf(sc - mm) : 0.f;
        float ll = ev_l;
#pragma unroll
        for (int off = 32; off; off >>= 1) ll += __shfl_xor(ll, off);
        l = ll;
        int j = 0;
        for (; j + 3 < cnt; j += 4) {
            int s0 = bcasti(s_l, j),     s1 = bcasti(s_l, j + 1);
            int s2 = bcasti(s_l, j + 2), s3 = bcasti(s_l, j + 3);
            float e0 = bcastf(ev_l, j),     e1 = bcastf(ev_l, j + 1);
            float e2 = bcastf(ev_l, j + 2), e3 = bcastf(ev_l, j + 3);
            acc0 += e0 * __half2float(hs[(size_t)s0 * H + lane]);
            acc1 += e1 * __half2float(hs[(size_t)s1 * H + lane]);
            acc2 += e2 * __half2float(hs[(size_t)s2 * H + lane]);
            acc3 += e3 * __half2float(hs[(size_t)s3 * H + lane]);
        }
        for (; j < cnt; ++j)
            acc0 += bcastf(ev_l, j) * __half2float(hs[(size_t)bcasti(s_l, j) * H + lane]);
    } else {
        float mm = -3.4e38f;
        for (int base = beg; base < end; base += 64) {
            int idx = base + lane;
            if (idx < end) {
                float sc = ssrc[srcs[idx]] + sdst;
                sc = sc > 0.f ? sc : 0.2f * sc;
                mm = fmaxf(mm, sc);
            }
        }
#pragma unroll
        for (int off = 32; off; off >>= 1) mm = fmaxf(mm, __shfl_xor(mm, off));
        float ll = 0.f;
        for (int base = beg; base < end; base += 64) {
            int idx = base + lane;
            int c2 = end - base; if (c2 > 64) c2 = 64;
            int s_l = idx < end ? srcs[idx] : 0;
            float ev_l = 0.f;
            if (idx < end) {
                float sc = ssrc[s_l] + sdst;
                sc = sc > 0.f ? sc : 0.2f * sc;
                ev_l = __expf(sc - mm);
            }
            ll += ev_l;
            int j = 0;
            for (; j + 1 < c2; j += 2) {
                acc0 += bcastf(ev_l, j) * __half2float(hs[(size_t)bcasti(s_l, j) * H + lane]);
                acc1 += bcastf(ev_l, j + 1) * __half2float(hs[(size_t)bcasti(s_l, j + 1) * H + lane]);
            }
            if (j < c2)
                acc0 += bcastf(ev_l, j) * __half2float(hs[(size_t)bcasti(s_l, j) * H + lane]);
        }
#pragma unroll
        for (int off = 32; off; off >>= 1) ll += __shfl_xor(ll, off);
        l = ll;
    }
    float v = ((acc0 + acc1) + (acc2 + acc3)) / (l + 1e-16f) + bias[lane];
    return v > 0.f ? v : 0.f;
}

__global__ void gat_node_kernel(const int* __restrict__ rowptr, const int* __restrict__ srcs,
                                const float* __restrict__ ssrc, const float* __restrict__ xdst,
                                const float* __restrict__ v2, const __half* __restrict__ hs,
                                const float* __restrict__ bias, float* __restrict__ out, int ndst) {
    int wid = (int)((blockIdx.x * blockDim.x + threadIdx.x) >> 6);
    int lane = threadIdx.x & 63;
    if (wid >= ndst) return;
    out[(size_t)wid * H + lane] = gat_aggregate(rowptr, srcs, ssrc, xdst, v2, hs, bias, wid, lane);
}

// final relation: GAT aggregation + fused MLP head
__global__ void gat_node_mlp_kernel(const int* __restrict__ rowptr, const int* __restrict__ srcs,
                                    const float* __restrict__ ssrc, const float* __restrict__ xdst,
                                    const float* __restrict__ v2, const __half* __restrict__ hs,
                                    const float* __restrict__ bias,
                                    const float* __restrict__ w1, const float* __restrict__ b1,
                                    const float* __restrict__ w2, const float* __restrict__ b2,
                                    float* __restrict__ out, int ndst) {
    __shared__ float W1[H * 32];
    __shared__ float W2[32];
    __shared__ float B1[32];
    {
        int t = threadIdx.x;
        for (int i = t; i < H * 32; i += 256) W1[i] = w1[i];
        if (t < 32) { W2[t] = w2[t]; B1[t] = b1[t]; }
        __syncthreads();
    }
    int wid = (int)((blockIdx.x * blockDim.x + threadIdx.x) >> 6);
    int lane = threadIdx.x & 63;
    if (wid >= ndst) return;
    float v = gat_aggregate(rowptr, srcs, ssrc, xdst, v2, hs, bias, wid, lane);

    int c = lane & 31;
    int kbase = (lane >> 5) << 5;
    float s = 0.f;
#pragma unroll
    for (int k = 0; k < 32; ++k) s += __shfl(v, kbase + k) * W1[(kbase + k) * 32 + c];
    s += __shfl_xor(s, 32);
    s += B1[c];
    s = s > 0.f ? s : 0.f;
    float q = s * W2[c];
#pragma unroll
    for (int off = 16; off; off >>= 1) q += __shfl_xor(q, off);
    if (lane == 0) out[wid] = q + b2[0];
}

extern "C" void kernel_launch(void* const* d_in, const int* in_sizes, int n_in,
                              void* d_out, int out_size, void* d_ws, size_t ws_size,
                              hipStream_t stream) {
    const float* x_inst  = (const float*)d_in[0];
    const float* x_net   = (const float*)d_in[1];
    const int*   e_i2n   = (const int*)d_in[2];
    const int*   e_n2i   = (const int*)d_in[3];
    const float* W_src   = (const float*)d_in[4];
    const float* W_dst   = (const float*)d_in[5];
    const float* att_src = (const float*)d_in[6];
    const float* att_dst = (const float*)d_in[7];
    const float* bias_g  = (const float*)d_in[8];
    const float* lin1_w  = (const float*)d_in[9];
    const float* lin1_b  = (const float*)d_in[10];
    const float* lin2_w  = (const float*)d_in[11];
    const float* lin2_b  = (const float*)d_in[12];

    const int n_inst = in_sizes[0] / H;
    const int n_net  = in_sizes[1] / H;
    const int ne     = in_sizes[2] / 2;
    const int nmax   = n_inst > n_net ? n_inst : n_net;

    float* ws = (float*)d_ws;
    size_t off = 0;
    auto alloc = [&](size_t nelem) { float* p = ws + off; off += nelem; return p; };
    float* xnA     = alloc((size_t)n_net * H);
    float* xiA     = alloc((size_t)n_inst * H);
    __half* hs     = (__half*)alloc((size_t)nmax * H / 2);  // fp16: half the floats
    float* ssrc    = alloc(nmax);
    int*   rp_i2n  = (int*)alloc(nmax + 1);
    int*   sr_i2n  = (int*)alloc(ne);
    int*   rp_n2i  = (int*)alloc(nmax + 1);
    int*   sr_n2i  = (int*)alloc(ne);
    int*   cur1    = (int*)alloc(nmax);
    int*   cur2    = (int*)alloc(nmax);
    int*   bsum    = (int*)alloc(1024);
    float* v2all   = alloc(3 * H);
    (void)ws_size;

    // ---- upfront: all three v2 vectors in one launch ----
    wvec3_kernel<<<3, 64, 0, stream>>>(W_dst, att_dst, v2all);

    // ---- build both CSRs (shared across layers) ----
    fill_zero<<<256, 256, 0, stream>>>((float*)cur1, nmax);
    fill_zero<<<256, 256, 0, stream>>>((float*)cur2, nmax);
    hist2_kernel<<<8192, 256, 0, stream>>>(e_i2n + ne, e_n2i + ne, cur1, cur2, ne);
    {
        int nb1 = (n_net + 255) / 256;
        scan_block<<<nb1, 256, 0, stream>>>(cur1, rp_i2n, bsum, n_net);
        scan_bsum<<<1, 1024, 0, stream>>>(bsum, nb1);
        add_offsets<<<(n_net + 256) / 256, 256, 0, stream>>>(rp_i2n, bsum, cur1, n_net, ne);
        int nb2 = (n_inst + 255) / 256;
        scan_block<<<nb2, 256, 0, stream>>>(cur2, rp_n2i, bsum, n_inst);
        scan_bsum<<<1, 1024, 0, stream>>>(bsum, nb2);
        add_offsets<<<(n_inst + 256) / 256, 256, 0, stream>>>(rp_n2i, bsum, cur2, n_inst, ne);
    }
    scatter2_kernel<<<8192, 256, 0, stream>>>(e_i2n, e_i2n + ne, cur1, sr_i2n,
                                              e_n2i, e_n2i + ne, cur2, sr_n2i, ne);

    auto proj = [&](const float* xsrc, int nsrc, int rel) {
        const float* Ws  = W_src + (size_t)rel * H * H;
        const float* as_ = att_src + (size_t)rel * H;
        gemm_hs_fused<<<(nsrc + 3) / 4, 256, 0, stream>>>(xsrc, Ws, as_, hs, ssrc, nsrc);
    };

    // layer 0, relation 0: inst -> net  (flat rel 0)
    proj(x_inst, n_inst, 0);
    gat_node_kernel<<<(n_net + 3) / 4, 256, 0, stream>>>(rp_i2n, sr_i2n, ssrc, x_net,
                                                         v2all + 0 * H, hs,
                                                         bias_g + 0 * H, xnA, n_net);
    // layer 0, relation 1: net -> inst  (flat rel 1)
    proj(x_net, n_net, 1);
    gat_node_kernel<<<(n_inst + 3) / 4, 256, 0, stream>>>(rp_n2i, sr_n2i, ssrc, x_inst,
                                                          v2all + 1 * H, hs,
                                                          bias_g + 1 * H, xiA, n_inst);
    // layer 1, relation 0: inst -> net, fused MLP head (flat rel 2; l1 inst-side dead)
    proj(xiA, n_inst, 2);
    gat_node_mlp_kernel<<<(n_net + 3) / 4, 256, 0, stream>>>(rp_i2n, sr_i2n, ssrc, xnA,
                                                             v2all + 2 * H, hs,
                                                             bias_g + 2 * H,
                                                             lin1_w, lin1_b, lin2_w, lin2_b,
                                                             (float*)d_out, n_net);
}

// Round 7
// 526.581 us; speedup vs baseline: 3.7410x; 1.5083x over previous
//
#include <hip/hip_runtime.h>
#include <hip/hip_fp16.h>

#define H 64
#define BSHIFT 7
#define BUCKET 128
#define MAXNB 1024
#define CHUNK 16384

__device__ __forceinline__ int bcasti(int x, int j) {
    return __builtin_amdgcn_readlane(x, j);
}
__device__ __forceinline__ float bcastf(float x, int j) {
    return __uint_as_float((unsigned)__builtin_amdgcn_readlane((int)__float_as_uint(x), j));
}

__global__ void fill_zero(float* __restrict__ p, int n) {
    int i = blockIdx.x * blockDim.x + threadIdx.x;
    int stride = gridDim.x * blockDim.x;
    for (; i < n; i += stride) p[i] = 0.f;
}

// v2all[b][k] = sum_j Wd_b[k][j] * ad_b[j]  for the 3 used relations
__global__ void wvec3_kernel(const float* __restrict__ W_dst, const float* __restrict__ att_dst,
                             float* __restrict__ v2all) {
    int b = blockIdx.x;
    int k = threadIdx.x;
    const float* Wd = W_dst + (size_t)b * H * H;
    const float* ad = att_dst + (size_t)b * H;
    float s2 = 0.f;
    for (int j = 0; j < H; ++j) s2 += Wd[k * H + j] * ad[j];
    v2all[b * H + k] = s2;
}

// hs = half(x @ W) ; ssrc = (x@W) . a_s   (one wave per row, W in LDS)
__global__ void gemm_hs_fused(const float* __restrict__ x, const float* __restrict__ W,
                              const float* __restrict__ as_, __half* __restrict__ hs,
                              float* __restrict__ ssrc, int n) {
    __shared__ float Wl[H * H];
    int t = threadIdx.x;
    for (int i = t; i < H * H; i += 256) Wl[i] = W[i];
    __syncthreads();
    int row = blockIdx.x * 4 + (t >> 6);
    int lane = t & 63;
    if (row >= n) return;
    float xr = x[(size_t)row * H + lane];
    float acc = 0.f;
#pragma unroll
    for (int k = 0; k < H; ++k) {
        acc += bcastf(xr, k) * Wl[k * H + lane];
    }
    hs[(size_t)row * H + lane] = __float2half_rn(acc);
    float p = acc * as_[lane];
#pragma unroll
    for (int off = 32; off; off >>= 1) p += __shfl_xor(p, off);
    if (lane == 0) ssrc[row] = p;
}

// ---- privatized multi-split CSR build ----
// K1: per-chunk LDS bucket histogram -> one global atomicAdd per (block,bucket)
__global__ void part_hist(const int* __restrict__ dstA, const int* __restrict__ dstB,
                          int* __restrict__ bcntA, int* __restrict__ bcntB,
                          int ne, int nch) {
    __shared__ int h[MAXNB];
    int b = blockIdx.x;
    bool second = b >= nch;
    const int* dst = second ? dstB : dstA;
    int* bcnt = second ? bcntB : bcntA;
    int c = second ? b - nch : b;
    int beg = c * CHUNK, end = beg + CHUNK;
    if (end > ne) end = ne;
    int t = threadIdx.x;
    for (int i = t; i < MAXNB; i += 256) h[i] = 0;
    __syncthreads();
    for (int i = beg + t; i < end; i += 256) atomicAdd(&h[dst[i] >> BSHIFT], 1);
    __syncthreads();
    for (int i = t; i < MAXNB; i += 256) if (h[i]) atomicAdd(&bcnt[i], h[i]);
}

// exclusive scan of bucket counts for both lists (block 0 = list A, block 1 = list B)
__global__ void bucket_scan2(const int* __restrict__ bcntA, const int* __restrict__ bcntB,
                             int* __restrict__ bstartA, int* __restrict__ bstartB,
                             int* __restrict__ bcurA, int* __restrict__ bcurB,
                             int nbA, int nbB, int ne) {
    __shared__ int sm[1024];
    const int* bcnt = blockIdx.x ? bcntB : bcntA;
    int* bstart = blockIdx.x ? bstartB : bstartA;
    int* bcur   = blockIdx.x ? bcurB : bcurA;
    int nb      = blockIdx.x ? nbB : nbA;
    int t = threadIdx.x;
    int c = t < nb ? bcnt[t] : 0;
    sm[t] = c;
    __syncthreads();
    for (int off = 1; off < 1024; off <<= 1) {
        int v = t >= off ? sm[t - off] : 0;
        __syncthreads();
        sm[t] += v;
        __syncthreads();
    }
    if (t < nb) { int e = sm[t] - c; bstart[t] = e; bcur[t] = e; }
    if (t == 0) bstart[nb] = ne;
}

// K2: re-hist chunk in LDS, reserve ranges (1 atomic per block,bucket), write records
__global__ void part_scatter(const int* __restrict__ srcA, const int* __restrict__ dstA,
                             int* __restrict__ bcurA, unsigned long long* __restrict__ tmpA,
                             const int* __restrict__ srcB, const int* __restrict__ dstB,
                             int* __restrict__ bcurB, unsigned long long* __restrict__ tmpB,
                             int ne, int nch) {
    __shared__ int h[MAXNB];
    __shared__ int cur[MAXNB];
    int b = blockIdx.x;
    bool second = b >= nch;
    const int* src = second ? srcB : srcA;
    const int* dst = second ? dstB : dstA;
    int* bcur = second ? bcurB : bcurA;
    unsigned long long* tmp = second ? tmpB : tmpA;
    int c = second ? b - nch : b;
    int beg = c * CHUNK, end = beg + CHUNK;
    if (end > ne) end = ne;
    int t = threadIdx.x;
    for (int i = t; i < MAXNB; i += 256) h[i] = 0;
    __syncthreads();
    for (int i = beg + t; i < end; i += 256) atomicAdd(&h[dst[i] >> BSHIFT], 1);
    __syncthreads();
    for (int i = t; i < MAXNB; i += 256)
        cur[i] = h[i] ? atomicAdd(&bcur[i], h[i]) : 0;
    __syncthreads();
    for (int i = beg + t; i < end; i += 256) {
        int d = dst[i];
        int pos = atomicAdd(&cur[d >> BSHIFT], 1);
        unsigned long long rec = ((unsigned long long)(unsigned)d << 32) | (unsigned)src[i];
        __builtin_nontemporal_store(rec, &tmp[pos]);
    }
}

// K3: one block per bucket; LDS count/scan its 128 dsts, emit rowptr, local re-scatter
__global__ void bucket_finalize2(const unsigned long long* __restrict__ tmpA,
                                 const int* __restrict__ bstartA,
                                 int* __restrict__ rowptrA, int* __restrict__ srcsA,
                                 int ndstA, int nbA,
                                 const unsigned long long* __restrict__ tmpB,
                                 const int* __restrict__ bstartB,
                                 int* __restrict__ rowptrB, int* __restrict__ srcsB,
                                 int ndstB) {
    __shared__ int cnt[BUCKET];
    __shared__ int sm[BUCKET];
    __shared__ int cur[BUCKET];
    int b = blockIdx.x;
    bool second = b >= nbA;
    const unsigned long long* tmp = second ? tmpB : tmpA;
    const int* bstart = second ? bstartB : bstartA;
    int* rowptr = second ? rowptrB : rowptrA;
    int* srcs   = second ? srcsB : srcsA;
    int ndst    = second ? ndstB : ndstA;
    if (second) b -= nbA;

    int t = threadIdx.x;
    int base = bstart[b], endi = bstart[b + 1];
    if (t < BUCKET) cnt[t] = 0;
    __syncthreads();
    for (int i = base + t; i < endi; i += 256) {
        int d = (int)(tmp[i] >> 32);
        atomicAdd(&cnt[d & (BUCKET - 1)], 1);
    }
    __syncthreads();
    if (t < BUCKET) sm[t] = cnt[t];
    __syncthreads();
    for (int off = 1; off < BUCKET; off <<= 1) {
        int v = (t < BUCKET && t >= off) ? sm[t - off] : 0;
        __syncthreads();
        if (t < BUCKET) sm[t] += v;
        __syncthreads();
    }
    int d0 = b << BSHIFT;
    if (t < BUCKET) {
        int e = base + sm[t] - cnt[t];
        cur[t] = e;
        if (d0 + t < ndst) rowptr[d0 + t] = e;
    }
    if (t == 0) {
        int hi = d0 + BUCKET;
        if (hi > ndst) hi = ndst;
        rowptr[hi] = endi;
    }
    __syncthreads();
    for (int i = base + t; i < endi; i += 256) {
        unsigned long long rec = tmp[i];
        int d = (int)(rec >> 32);
        int s = (int)(rec & 0xffffffffu);
        int pos = atomicAdd(&cur[d & (BUCKET - 1)], 1);
        srcs[pos] = s;
    }
}

// ---- fused per-dst-node GAT aggregation, two-phase softmax, fp16 hs gather ----
__device__ __forceinline__ float gat_aggregate(const int* __restrict__ rowptr,
                                               const int* __restrict__ srcs,
                                               const float* __restrict__ ssrc,
                                               const float* __restrict__ xdst,
                                               const float* __restrict__ v2,
                                               const __half* __restrict__ hs,
                                               const float* __restrict__ bias,
                                               int wid, int lane) {
    float p = xdst[(size_t)wid * H + lane] * v2[lane];
#pragma unroll
    for (int off = 32; off; off >>= 1) p += __shfl_xor(p, off);
    float sdst = p;

    int beg = rowptr[wid], end = rowptr[wid + 1];
    int cnt = end - beg;
    float acc0 = 0.f, acc1 = 0.f, acc2 = 0.f, acc3 = 0.f, l;

    if (cnt <= 64) {
        bool valid = lane < cnt;
        int s_l = valid ? srcs[beg + lane] : 0;
        float sc = ssrc[s_l] + sdst;
        sc = sc > 0.f ? sc : 0.2f * sc;
        float mm = valid ? sc : -3.4e38f;
#pragma unroll
        for (int off = 32; off; off >>= 1) mm = fmaxf(mm, __shfl_xor(mm, off));
        float ev_l = valid ? __expf(sc - mm) : 0.f;
        float ll = ev_l;
#pragma unroll
        for (int off = 32; off; off >>= 1) ll += __shfl_xor(ll, off);
        l = ll;
        int j = 0;
        for (; j + 3 < cnt; j += 4) {
            int s0 = bcasti(s_l, j),     s1 = bcasti(s_l, j + 1);
            int s2 = bcasti(s_l, j + 2), s3 = bcasti(s_l, j + 3);
            float e0 = bcastf(ev_l, j),     e1 = bcastf(ev_l, j + 1);
            float e2 = bcastf(ev_l, j + 2), e3 = bcastf(ev_l, j + 3);
            acc0 += e0 * __half2float(hs[(size_t)s0 * H + lane]);
            acc1 += e1 * __half2float(hs[(size_t)s1 * H + lane]);
            acc2 += e2 * __half2float(hs[(size_t)s2 * H + lane]);
            acc3 += e3 * __half2float(hs[(size_t)s3 * H + lane]);
        }
        for (; j < cnt; ++j)
            acc0 += bcastf(ev_l, j) * __half2float(hs[(size_t)bcasti(s_l, j) * H + lane]);
    } else {
        float mm = -3.4e38f;
        for (int base = beg; base < end; base += 64) {
            int idx = base + lane;
            if (idx < end) {
                float sc = ssrc[srcs[idx]] + sdst;
                sc = sc > 0.f ? sc : 0.2f * sc;
                mm = fmaxf(mm, sc);
            }
        }
#pragma unroll
        for (int off = 32; off; off >>= 1) mm = fmaxf(mm, __shfl_xor(mm, off));
        float ll = 0.f;
        for (int base = beg; base < end; base += 64) {
            int idx = base + lane;
            int c2 = end - base; if (c2 > 64) c2 = 64;
            int s_l = idx < end ? srcs[idx] : 0;
            float ev_l = 0.f;
            if (idx < end) {
                float sc = ssrc[s_l] + sdst;
                sc = sc > 0.f ? sc : 0.2f * sc;
                ev_l = __expf(sc - mm);
            }
            ll += ev_l;
            int j = 0;
            for (; j + 1 < c2; j += 2) {
                acc0 += bcastf(ev_l, j) * __half2float(hs[(size_t)bcasti(s_l, j) * H + lane]);
                acc1 += bcastf(ev_l, j + 1) * __half2float(hs[(size_t)bcasti(s_l, j + 1) * H + lane]);
            }
            if (j < c2)
                acc0 += bcastf(ev_l, j) * __half2float(hs[(size_t)bcasti(s_l, j) * H + lane]);
        }
#pragma unroll
        for (int off = 32; off; off >>= 1) ll += __shfl_xor(ll, off);
        l = ll;
    }
    float v = ((acc0 + acc1) + (acc2 + acc3)) / (l + 1e-16f) + bias[lane];
    return v > 0.f ? v : 0.f;
}

__global__ void gat_node_kernel(const int* __restrict__ rowptr, const int* __restrict__ srcs,
                                const float* __restrict__ ssrc, const float* __restrict__ xdst,
                                const float* __restrict__ v2, const __half* __restrict__ hs,
                                const float* __restrict__ bias, float* __restrict__ out, int ndst) {
    int wid = (int)((blockIdx.x * blockDim.x + threadIdx.x) >> 6);
    int lane = threadIdx.x & 63;
    if (wid >= ndst) return;
    out[(size_t)wid * H + lane] = gat_aggregate(rowptr, srcs, ssrc, xdst, v2, hs, bias, wid, lane);
}

// final relation: GAT aggregation + fused MLP head
__global__ void gat_node_mlp_kernel(const int* __restrict__ rowptr, const int* __restrict__ srcs,
                                    const float* __restrict__ ssrc, const float* __restrict__ xdst,
                                    const float* __restrict__ v2, const __half* __restrict__ hs,
                                    const float* __restrict__ bias,
                                    const float* __restrict__ w1, const float* __restrict__ b1,
                                    const float* __restrict__ w2, const float* __restrict__ b2,
                                    float* __restrict__ out, int ndst) {
    __shared__ float W1[H * 32];
    __shared__ float W2[32];
    __shared__ float B1[32];
    {
        int t = threadIdx.x;
        for (int i = t; i < H * 32; i += 256) W1[i] = w1[i];
        if (t < 32) { W2[t] = w2[t]; B1[t] = b1[t]; }
        __syncthreads();
    }
    int wid = (int)((blockIdx.x * blockDim.x + threadIdx.x) >> 6);
    int lane = threadIdx.x & 63;
    if (wid >= ndst) return;
    float v = gat_aggregate(rowptr, srcs, ssrc, xdst, v2, hs, bias, wid, lane);

    int c = lane & 31;
    int kbase = (lane >> 5) << 5;
    float s = 0.f;
#pragma unroll
    for (int k = 0; k < 32; ++k) s += __shfl(v, kbase + k) * W1[(kbase + k) * 32 + c];
    s += __shfl_xor(s, 32);
    s += B1[c];
    s = s > 0.f ? s : 0.f;
    float q = s * W2[c];
#pragma unroll
    for (int off = 16; off; off >>= 1) q += __shfl_xor(q, off);
    if (lane == 0) out[wid] = q + b2[0];
}

extern "C" void kernel_launch(void* const* d_in, const int* in_sizes, int n_in,
                              void* d_out, int out_size, void* d_ws, size_t ws_size,
                              hipStream_t stream) {
    const float* x_inst  = (const float*)d_in[0];
    const float* x_net   = (const float*)d_in[1];
    const int*   e_i2n   = (const int*)d_in[2];
    const int*   e_n2i   = (const int*)d_in[3];
    const float* W_src   = (const float*)d_in[4];
    const float* W_dst   = (const float*)d_in[5];
    const float* att_src = (const float*)d_in[6];
    const float* att_dst = (const float*)d_in[7];
    const float* bias_g  = (const float*)d_in[8];
    const float* lin1_w  = (const float*)d_in[9];
    const float* lin1_b  = (const float*)d_in[10];
    const float* lin2_w  = (const float*)d_in[11];
    const float* lin2_b  = (const float*)d_in[12];

    const int n_inst = in_sizes[0] / H;
    const int n_net  = in_sizes[1] / H;
    const int ne     = in_sizes[2] / 2;
    const int nmax   = n_inst > n_net ? n_inst : n_net;

    float* ws = (float*)d_ws;
    size_t off = 0;
    auto alloc = [&](size_t nelem) {
        off = (off + 1) & ~(size_t)1;   // 8B alignment
        float* p = ws + off; off += nelem; return p;
    };
    float* xnA     = alloc((size_t)n_net * H);
    float* xiA     = alloc((size_t)n_inst * H);
    __half* hs     = (__half*)alloc((size_t)nmax * H / 2);
    float* ssrc    = alloc(nmax);
    int*   rp_i2n  = (int*)alloc(nmax + 1);
    int*   sr_i2n  = (int*)alloc(ne);
    int*   rp_n2i  = (int*)alloc(nmax + 1);
    int*   sr_n2i  = (int*)alloc(ne);
    unsigned long long* tmpA = (unsigned long long*)alloc((size_t)ne * 2);
    unsigned long long* tmpB = (unsigned long long*)alloc((size_t)ne * 2);
    int*   bcntA   = (int*)alloc(MAXNB + 1);
    int*   bcntB   = (int*)alloc(MAXNB + 1);
    int*   bstartA = (int*)alloc(MAXNB + 1);
    int*   bstartB = (int*)alloc(MAXNB + 1);
    int*   bcurA   = (int*)alloc(MAXNB + 1);
    int*   bcurB   = (int*)alloc(MAXNB + 1);
    float* v2all   = alloc(3 * H);
    (void)ws_size;

    const int* dstA = e_i2n + ne;   // dst = net
    const int* dstB = e_n2i + ne;   // dst = inst
    const int nbA = (n_net + BUCKET - 1) >> BSHIFT;
    const int nbB = (n_inst + BUCKET - 1) >> BSHIFT;
    const int nch = (ne + CHUNK - 1) / CHUNK;

    // ---- upfront small kernels ----
    wvec3_kernel<<<3, 64, 0, stream>>>(W_dst, att_dst, v2all);
    fill_zero<<<2, 256, 0, stream>>>((float*)bcntA, MAXNB);
    fill_zero<<<2, 256, 0, stream>>>((float*)bcntB, MAXNB);

    // ---- privatized multi-split CSR build (both edge lists in each launch) ----
    part_hist<<<2 * nch, 256, 0, stream>>>(dstA, dstB, bcntA, bcntB, ne, nch);
    bucket_scan2<<<2, 1024, 0, stream>>>(bcntA, bcntB, bstartA, bstartB,
                                         bcurA, bcurB, nbA, nbB, ne);
    part_scatter<<<2 * nch, 256, 0, stream>>>(e_i2n, dstA, bcurA, tmpA,
                                              e_n2i, dstB, bcurB, tmpB, ne, nch);
    bucket_finalize2<<<nbA + nbB, 256, 0, stream>>>(tmpA, bstartA, rp_i2n, sr_i2n, n_net, nbA,
                                                    tmpB, bstartB, rp_n2i, sr_n2i, n_inst);

    auto proj = [&](const float* xsrc, int nsrc, int rel) {
        const float* Ws  = W_src + (size_t)rel * H * H;
        const float* as_ = att_src + (size_t)rel * H;
        gemm_hs_fused<<<(nsrc + 3) / 4, 256, 0, stream>>>(xsrc, Ws, as_, hs, ssrc, nsrc);
    };

    // layer 0, relation 0: inst -> net
    proj(x_inst, n_inst, 0);
    gat_node_kernel<<<(n_net + 3) / 4, 256, 0, stream>>>(rp_i2n, sr_i2n, ssrc, x_net,
                                                         v2all + 0 * H, hs,
                                                         bias_g + 0 * H, xnA, n_net);
    // layer 0, relation 1: net -> inst
    proj(x_net, n_net, 1);
    gat_node_kernel<<<(n_inst + 3) / 4, 256, 0, stream>>>(rp_n2i, sr_n2i, ssrc, x_inst,
                                                          v2all + 1 * H, hs,
                                                          bias_g + 1 * H, xiA, n_inst);
    // layer 1, relation 0: inst -> net, fused MLP head (l1 inst-side dead)
    proj(xiA, n_inst, 2);
    gat_node_mlp_kernel<<<(n_net + 3) / 4, 256, 0, stream>>>(rp_i2n, sr_i2n, ssrc, xnA,
                                                             v2all + 2 * H, hs,
                                                             bias_g + 2 * H,
                                                             lin1_w, lin1_b, lin2_w, lin2_b,
                                                             (float*)d_out, n_net);
}

// Round 8
// 480.811 us; speedup vs baseline: 4.0971x; 1.0952x over previous
//
#include <hip/hip_runtime.h>
#include <hip/hip_fp16.h>

#define H 64
#define BSHIFT 9
#define BUCKET 512
#define NBMAX 256
#define CHUNK 4096

__device__ __forceinline__ int bcasti(int x, int j) {
    return __builtin_amdgcn_readlane(x, j);
}
__device__ __forceinline__ float bcastf(float x, int j) {
    return __uint_as_float((unsigned)__builtin_amdgcn_readlane((int)__float_as_uint(x), j));
}

// v2all[b][k] = sum_j Wd_b[k][j] * ad_b[j]  for the 3 used relations
__global__ void wvec3_kernel(const float* __restrict__ W_dst, const float* __restrict__ att_dst,
                             float* __restrict__ v2all) {
    int b = blockIdx.x;
    int k = threadIdx.x;
    const float* Wd = W_dst + (size_t)b * H * H;
    const float* ad = att_dst + (size_t)b * H;
    float s2 = 0.f;
    for (int j = 0; j < H; ++j) s2 += Wd[k * H + j] * ad[j];
    v2all[b * H + k] = s2;
}

// hs = half(x @ W) ; ssrc = (x@W) . a_s   (one wave per row, W in LDS)
__global__ void gemm_hs_fused(const float* __restrict__ x, const float* __restrict__ W,
                              const float* __restrict__ as_, __half* __restrict__ hs,
                              float* __restrict__ ssrc, int n) {
    __shared__ float Wl[H * H];
    int t = threadIdx.x;
    for (int i = t; i < H * H; i += 256) Wl[i] = W[i];
    __syncthreads();
    int row = blockIdx.x * 4 + (t >> 6);
    int lane = t & 63;
    if (row >= n) return;
    float xr = x[(size_t)row * H + lane];
    float acc = 0.f;
#pragma unroll
    for (int k = 0; k < H; ++k) {
        acc += bcastf(xr, k) * Wl[k * H + lane];
    }
    hs[(size_t)row * H + lane] = __float2half_rn(acc);
    float p = acc * as_[lane];
#pragma unroll
    for (int off = 32; off; off >>= 1) p += __shfl_xor(p, off);
    if (lane == 0) ssrc[row] = p;
}

// ---- atomic-free counting-sort CSR build ----
// K1: per-chunk LDS bucket histogram -> plain stores to cnt[bucket][chunk]
__global__ void part_hist(const int* __restrict__ dstA, const int* __restrict__ dstB,
                          int* __restrict__ cntA, int* __restrict__ cntB,
                          int ne, int nch, int nbA, int nbB) {
    __shared__ int h[NBMAX];
    int blk = blockIdx.x;
    bool second = blk >= nch;
    const int* dst = second ? dstB : dstA;
    int* cnt = second ? cntB : cntA;
    int nb = second ? nbB : nbA;
    int c = second ? blk - nch : blk;
    int beg = c * CHUNK, end = beg + CHUNK;
    if (end > ne) end = ne;
    int t = threadIdx.x;
    for (int i = t; i < NBMAX; i += 256) h[i] = 0;
    __syncthreads();
    for (int i = beg + t; i < end; i += 256) atomicAdd(&h[dst[i] >> BSHIFT], 1);
    __syncthreads();
    for (int b = t; b < nb; b += 256) cnt[(size_t)b * nch + c] = h[b];
}

// K2: per-bucket exclusive scan over its chunk counts (in place); total[b] out.
// 512 threads; requires nch <= 512.
__global__ void scan_chunks(int* __restrict__ cntA, int* __restrict__ cntB,
                            int* __restrict__ totA, int* __restrict__ totB,
                            int nch, int nbA) {
    __shared__ int sm[512];
    int b = blockIdx.x;
    bool second = b >= nbA;
    int* cnt = second ? cntB : cntA;
    int* tot = second ? totB : totA;
    if (second) b -= nbA;
    int t = threadIdx.x;
    int v = t < nch ? cnt[(size_t)b * nch + t] : 0;
    sm[t] = v;
    __syncthreads();
    for (int off = 1; off < 512; off <<= 1) {
        int u = t >= off ? sm[t - off] : 0;
        __syncthreads();
        sm[t] += u;
        __syncthreads();
    }
    if (t < nch) cnt[(size_t)b * nch + t] = sm[t] - v;
    if (t == 511) tot[b] = sm[511];
}

// K3: exclusive scan of bucket totals -> bstart (block 0 = list A, block 1 = list B)
__global__ void scan_buckets(const int* __restrict__ totA, const int* __restrict__ totB,
                             int* __restrict__ bstartA, int* __restrict__ bstartB,
                             int nbA, int nbB, int ne) {
    __shared__ int sm[256];
    const int* tot = blockIdx.x ? totB : totA;
    int* bstart = blockIdx.x ? bstartB : bstartA;
    int nb = blockIdx.x ? nbB : nbA;
    int t = threadIdx.x;
    int v = t < nb ? tot[t] : 0;
    sm[t] = v;
    __syncthreads();
    for (int off = 1; off < 256; off <<= 1) {
        int u = t >= off ? sm[t - off] : 0;
        __syncthreads();
        sm[t] += u;
        __syncthreads();
    }
    if (t < nb) bstart[t] = sm[t] - v;
    if (t == 0) bstart[nb] = ne;
}

// K5: scatter packed 4B records into precomputed per-(chunk,bucket) windows. No global atomics.
__global__ void part_scatter(const int* __restrict__ srcA, const int* __restrict__ dstA,
                             const int* __restrict__ cntA, const int* __restrict__ bstartA,
                             unsigned* __restrict__ tmpA,
                             const int* __restrict__ srcB, const int* __restrict__ dstB,
                             const int* __restrict__ cntB, const int* __restrict__ bstartB,
                             unsigned* __restrict__ tmpB,
                             int ne, int nch, int nbA, int nbB) {
    __shared__ int cur[NBMAX];
    int blk = blockIdx.x;
    bool second = blk >= nch;
    const int* src = second ? srcB : srcA;
    const int* dst = second ? dstB : dstA;
    const int* cnt = second ? cntB : cntA;
    const int* bstart = second ? bstartB : bstartA;
    unsigned* tmp = second ? tmpB : tmpA;
    int nb = second ? nbB : nbA;
    int c = second ? blk - nch : blk;
    int beg = c * CHUNK, end = beg + CHUNK;
    if (end > ne) end = ne;
    int t = threadIdx.x;
    for (int b = t; b < nb; b += 256) cur[b] = bstart[b] + cnt[(size_t)b * nch + c];
    __syncthreads();
    for (int i = beg + t; i < end; i += 256) {
        int d = dst[i];
        int pos = atomicAdd(&cur[d >> BSHIFT], 1);
        unsigned rec = ((unsigned)(d & (BUCKET - 1)) << 17) | (unsigned)src[i];
        __builtin_nontemporal_store(rec, &tmp[pos]);
    }
}

// K6: one block (512 thr) per bucket; LDS count/scan 512 dsts, emit rowptr, local re-scatter
__global__ void bucket_finalize(const unsigned* __restrict__ tmpA, const int* __restrict__ bstartA,
                                int* __restrict__ rowptrA, int* __restrict__ srcsA,
                                int ndstA, int nbA,
                                const unsigned* __restrict__ tmpB, const int* __restrict__ bstartB,
                                int* __restrict__ rowptrB, int* __restrict__ srcsB,
                                int ndstB) {
    __shared__ int cnt[BUCKET];
    __shared__ int sm[BUCKET];
    __shared__ int cur[BUCKET];
    int b = blockIdx.x;
    bool second = b >= nbA;
    const unsigned* tmp = second ? tmpB : tmpA;
    const int* bstart = second ? bstartB : bstartA;
    int* rowptr = second ? rowptrB : rowptrA;
    int* srcs   = second ? srcsB : srcsA;
    int ndst    = second ? ndstB : ndstA;
    if (second) b -= nbA;

    int t = threadIdx.x;
    int base = bstart[b], endi = bstart[b + 1];
    cnt[t] = 0;
    __syncthreads();
    for (int i = base + t; i < endi; i += 512)
        atomicAdd(&cnt[tmp[i] >> 17], 1);
    __syncthreads();
    int c0 = cnt[t];
    sm[t] = c0;
    __syncthreads();
    for (int off = 1; off < 512; off <<= 1) {
        int u = t >= off ? sm[t - off] : 0;
        __syncthreads();
        sm[t] += u;
        __syncthreads();
    }
    int d0 = b << BSHIFT;
    int e = base + sm[t] - c0;
    cur[t] = e;
    if (d0 + t < ndst) rowptr[d0 + t] = e;
    if (t == 0) {
        int hi = d0 + BUCKET;
        if (hi > ndst) hi = ndst;
        rowptr[hi] = endi;
    }
    __syncthreads();
    for (int i = base + t; i < endi; i += 512) {
        unsigned rec = tmp[i];
        int pos = atomicAdd(&cur[rec >> 17], 1);
        srcs[pos] = (int)(rec & 0x1FFFFu);
    }
}

// ---- fused per-dst-node GAT aggregation, two-phase softmax, fp16 hs gather ----
__device__ __forceinline__ float gat_aggregate(const int* __restrict__ rowptr,
                                               const int* __restrict__ srcs,
                                               const float* __restrict__ ssrc,
                                               const float* __restrict__ xdst,
                                               const float* __restrict__ v2,
                                               const __half* __restrict__ hs,
                                               const float* __restrict__ bias,
                                               int wid, int lane) {
    float p = xdst[(size_t)wid * H + lane] * v2[lane];
#pragma unroll
    for (int off = 32; off; off >>= 1) p += __shfl_xor(p, off);
    float sdst = p;

    int beg = rowptr[wid], end = rowptr[wid + 1];
    int cnt = end - beg;
    float acc0 = 0.f, acc1 = 0.f, acc2 = 0.f, acc3 = 0.f, l;

    if (cnt <= 64) {
        bool valid = lane < cnt;
        int s_l = valid ? srcs[beg + lane] : 0;
        float sc = ssrc[s_l] + sdst;
        sc = sc > 0.f ? sc : 0.2f * sc;
        float mm = valid ? sc : -3.4e38f;
#pragma unroll
        for (int off = 32; off; off >>= 1) mm = fmaxf(mm, __shfl_xor(mm, off));
        float ev_l = valid ? __expf(sc - mm) : 0.f;
        float ll = ev_l;
#pragma unroll
        for (int off = 32; off; off >>= 1) ll += __shfl_xor(ll, off);
        l = ll;
        int j = 0;
        for (; j + 3 < cnt; j += 4) {
            int s0 = bcasti(s_l, j),     s1 = bcasti(s_l, j + 1);
            int s2 = bcasti(s_l, j + 2), s3 = bcasti(s_l, j + 3);
            float e0 = bcastf(ev_l, j),     e1 = bcastf(ev_l, j + 1);
            float e2 = bcastf(ev_l, j + 2), e3 = bcastf(ev_l, j + 3);
            acc0 += e0 * __half2float(hs[(size_t)s0 * H + lane]);
            acc1 += e1 * __half2float(hs[(size_t)s1 * H + lane]);
            acc2 += e2 * __half2float(hs[(size_t)s2 * H + lane]);
            acc3 += e3 * __half2float(hs[(size_t)s3 * H + lane]);
        }
        for (; j < cnt; ++j)
            acc0 += bcastf(ev_l, j) * __half2float(hs[(size_t)bcasti(s_l, j) * H + lane]);
    } else {
        float mm = -3.4e38f;
        for (int base = beg; base < end; base += 64) {
            int idx = base + lane;
            if (idx < end) {
                float sc = ssrc[srcs[idx]] + sdst;
                sc = sc > 0.f ? sc : 0.2f * sc;
                mm = fmaxf(mm, sc);
            }
        }
#pragma unroll
        for (int off = 32; off; off >>= 1) mm = fmaxf(mm, __shfl_xor(mm, off));
        float ll = 0.f;
        for (int base = beg; base < end; base += 64) {
            int idx = base + lane;
            int c2 = end - base; if (c2 > 64) c2 = 64;
            int s_l = idx < end ? srcs[idx] : 0;
            float ev_l = 0.f;
            if (idx < end) {
                float sc = ssrc[s_l] + sdst;
                sc = sc > 0.f ? sc : 0.2f * sc;
                ev_l = __expf(sc - mm);
            }
            ll += ev_l;
            int j = 0;
            for (; j + 1 < c2; j += 2) {
                acc0 += bcastf(ev_l, j) * __half2float(hs[(size_t)bcasti(s_l, j) * H + lane]);
                acc1 += bcastf(ev_l, j + 1) * __half2float(hs[(size_t)bcasti(s_l, j + 1) * H + lane]);
            }
            if (j < c2)
                acc0 += bcastf(ev_l, j) * __half2float(hs[(size_t)bcasti(s_l, j) * H + lane]);
        }
#pragma unroll
        for (int off = 32; off; off >>= 1) ll += __shfl_xor(ll, off);
        l = ll;
    }
    float v = ((acc0 + acc1) + (acc2 + acc3)) / (l + 1e-16f) + bias[lane];
    return v > 0.f ? v : 0.f;
}

__global__ void gat_node_kernel(const int* __restrict__ rowptr, const int* __restrict__ srcs,
                                const float* __restrict__ ssrc, const float* __restrict__ xdst,
                                const float* __restrict__ v2, const __half* __restrict__ hs,
                                const float* __restrict__ bias, float* __restrict__ out, int ndst) {
    int wid = (int)((blockIdx.x * blockDim.x + threadIdx.x) >> 6);
    int lane = threadIdx.x & 63;
    if (wid >= ndst) return;
    out[(size_t)wid * H + lane] = gat_aggregate(rowptr, srcs, ssrc, xdst, v2, hs, bias, wid, lane);
}

// final relation: GAT aggregation + fused MLP head
__global__ void gat_node_mlp_kernel(const int* __restrict__ rowptr, const int* __restrict__ srcs,
                                    const float* __restrict__ ssrc, const float* __restrict__ xdst,
                                    const float* __restrict__ v2, const __half* __restrict__ hs,
                                    const float* __restrict__ bias,
                                    const float* __restrict__ w1, const float* __restrict__ b1,
                                    const float* __restrict__ w2, const float* __restrict__ b2,
                                    float* __restrict__ out, int ndst) {
    __shared__ float W1[H * 32];
    __shared__ float W2[32];
    __shared__ float B1[32];
    {
        int t = threadIdx.x;
        for (int i = t; i < H * 32; i += 256) W1[i] = w1[i];
        if (t < 32) { W2[t] = w2[t]; B1[t] = b1[t]; }
        __syncthreads();
    }
    int wid = (int)((blockIdx.x * blockDim.x + threadIdx.x) >> 6);
    int lane = threadIdx.x & 63;
    if (wid >= ndst) return;
    float v = gat_aggregate(rowptr, srcs, ssrc, xdst, v2, hs, bias, wid, lane);

    int c = lane & 31;
    int kbase = (lane >> 5) << 5;
    float s = 0.f;
#pragma unroll
    for (int k = 0; k < 32; ++k) s += __shfl(v, kbase + k) * W1[(kbase + k) * 32 + c];
    s += __shfl_xor(s, 32);
    s += B1[c];
    s = s > 0.f ? s : 0.f;
    float q = s * W2[c];
#pragma unroll
    for (int off = 16; off; off >>= 1) q += __shfl_xor(q, off);
    if (lane == 0) out[wid] = q + b2[0];
}

extern "C" void kernel_launch(void* const* d_in, const int* in_sizes, int n_in,
                              void* d_out, int out_size, void* d_ws, size_t ws_size,
                              hipStream_t stream) {
    const float* x_inst  = (const float*)d_in[0];
    const float* x_net   = (const float*)d_in[1];
    const int*   e_i2n   = (const int*)d_in[2];
    const int*   e_n2i   = (const int*)d_in[3];
    const float* W_src   = (const float*)d_in[4];
    const float* W_dst   = (const float*)d_in[5];
    const float* att_src = (const float*)d_in[6];
    const float* att_dst = (const float*)d_in[7];
    const float* bias_g  = (const float*)d_in[8];
    const float* lin1_w  = (const float*)d_in[9];
    const float* lin1_b  = (const float*)d_in[10];
    const float* lin2_w  = (const float*)d_in[11];
    const float* lin2_b  = (const float*)d_in[12];

    const int n_inst = in_sizes[0] / H;
    const int n_net  = in_sizes[1] / H;
    const int ne     = in_sizes[2] / 2;
    const int nmax   = n_inst > n_net ? n_inst : n_net;

    const int nbA = (n_net + BUCKET - 1) >> BSHIFT;
    const int nbB = (n_inst + BUCKET - 1) >> BSHIFT;
    const int nch = (ne + CHUNK - 1) / CHUNK;   // must be <= 512 (scan_chunks width)

    float* ws = (float*)d_ws;
    size_t off = 0;
    auto alloc = [&](size_t nelem) {
        off = (off + 1) & ~(size_t)1;
        float* p = ws + off; off += nelem; return p;
    };
    float* xnA     = alloc((size_t)n_net * H);
    float* xiA     = alloc((size_t)n_inst * H);
    __half* hs     = (__half*)alloc((size_t)nmax * H / 2);
    float* ssrc    = alloc(nmax);
    int*   rp_i2n  = (int*)alloc(nmax + 1);
    int*   sr_i2n  = (int*)alloc(ne);
    int*   rp_n2i  = (int*)alloc(nmax + 1);
    int*   sr_n2i  = (int*)alloc(ne);
    unsigned* tmpA = (unsigned*)alloc(ne);
    unsigned* tmpB = (unsigned*)alloc(ne);
    int*   cntA    = (int*)alloc((size_t)NBMAX * nch);
    int*   cntB    = (int*)alloc((size_t)NBMAX * nch);
    int*   totA    = (int*)alloc(NBMAX);
    int*   totB    = (int*)alloc(NBMAX);
    int*   bstartA = (int*)alloc(NBMAX + 1);
    int*   bstartB = (int*)alloc(NBMAX + 1);
    float* v2all   = alloc(3 * H);
    (void)ws_size;

    const int* dstA = e_i2n + ne;   // dst = net
    const int* dstB = e_n2i + ne;   // dst = inst

    // ---- upfront ----
    wvec3_kernel<<<3, 64, 0, stream>>>(W_dst, att_dst, v2all);

    // ---- atomic-free counting-sort CSR build (both lists per launch) ----
    part_hist<<<2 * nch, 256, 0, stream>>>(dstA, dstB, cntA, cntB, ne, nch, nbA, nbB);
    scan_chunks<<<nbA + nbB, 512, 0, stream>>>(cntA, cntB, totA, totB, nch, nbA);
    scan_buckets<<<2, 256, 0, stream>>>(totA, totB, bstartA, bstartB, nbA, nbB, ne);
    part_scatter<<<2 * nch, 256, 0, stream>>>(e_i2n, dstA, cntA, bstartA, tmpA,
                                              e_n2i, dstB, cntB, bstartB, tmpB,
                                              ne, nch, nbA, nbB);
    bucket_finalize<<<nbA + nbB, 512, 0, stream>>>(tmpA, bstartA, rp_i2n, sr_i2n, n_net, nbA,
                                                   tmpB, bstartB, rp_n2i, sr_n2i, n_inst);

    auto proj = [&](const float* xsrc, int nsrc, int rel) {
        const float* Ws  = W_src + (size_t)rel * H * H;
        const float* as_ = att_src + (size_t)rel * H;
        gemm_hs_fused<<<(nsrc + 3) / 4, 256, 0, stream>>>(xsrc, Ws, as_, hs, ssrc, nsrc);
    };

    // layer 0, relation 0: inst -> net
    proj(x_inst, n_inst, 0);
    gat_node_kernel<<<(n_net + 3) / 4, 256, 0, stream>>>(rp_i2n, sr_i2n, ssrc, x_net,
                                                         v2all + 0 * H, hs,
                                                         bias_g + 0 * H, xnA, n_net);
    // layer 0, relation 1: net -> inst
    proj(x_net, n_net, 1);
    gat_node_kernel<<<(n_inst + 3) / 4, 256, 0, stream>>>(rp_n2i, sr_n2i, ssrc, x_inst,
                                                          v2all + 1 * H, hs,
                                                          bias_g + 1 * H, xiA, n_inst);
    // layer 1, relation 0: inst -> net, fused MLP head (l1 inst-side dead)
    proj(xiA, n_inst, 2);
    gat_node_mlp_kernel<<<(n_net + 3) / 4, 256, 0, stream>>>(rp_i2n, sr_i2n, ssrc, xnA,
                                                             v2all + 2 * H, hs,
                                                             bias_g + 2 * H,
                                                             lin1_w, lin1_b, lin2_w, lin2_b,
                                                             (float*)d_out, n_net);
}